// Round 1
// baseline (426.747 us; speedup 1.0000x reference)
//
#include <hip/hip_runtime.h>
#include <math.h>

// Problem constants (from setup_inputs): B=8, D=8, H=256, W=256, M=256
#define HWPIX 65536   // 256*256
#define NCH   8
#define NMATCH 256
#define THETA_LEN 169

__device__ __forceinline__ float gelu_exact(float v) {
    return 0.5f * v * (1.0f + erff(v * 0.70710678118654752f));
}

__global__ __launch_bounds__(256) void dmh_kernel(
    const float* __restrict__ E,       // (8, 8, 256, 256)
    const float* __restrict__ theta,   // (256, 169)
    const float* __restrict__ centers, // (256, 2)
    const int*   __restrict__ bidx,    // (256,)
    float* __restrict__ out)           // (256, 256, 256)
{
    // Each block: one match m, one tile of 1024 pixels (4 pixels/thread).
    const int tiles_per_match = HWPIX / 1024; // 64
    const int m    = blockIdx.x / tiles_per_match;
    const int tile = blockIdx.x % tiles_per_match;

    __shared__ float th[THETA_LEN];
    __shared__ float sc[2];
    __shared__ int   sb;
    if (threadIdx.x < THETA_LEN) th[threadIdx.x] = theta[m * THETA_LEN + threadIdx.x];
    if (threadIdx.x < 2)         sc[threadIdx.x] = centers[m * 2 + threadIdx.x];
    if (threadIdx.x == 0)        sb = bidx[m];
    __syncthreads();

    const float cx = sc[0];
    const float cy = sc[1];
    const float* __restrict__ Eb = E + (long)sb * (NCH * HWPIX);

    const int pbase = tile * 1024 + threadIdx.x;

    #pragma unroll
    for (int k = 0; k < 4; ++k) {
        const int p = pbase + k * 256;
        const int h = p >> 8;
        const int w = p & 255;

        float x[10];
        #pragma unroll
        for (int c = 0; c < NCH; ++c) x[c] = Eb[c * HWPIX + p];
        // rel channel 0 = grid_x - cx, channel 1 = grid_y - cy
        x[8] = (w + 0.5f) * (1.0f / 256.0f) - cx;
        x[9] = (h + 0.5f) * (1.0f / 256.0f) - cy;

        // Layer 0: 10 -> 8, w0 = th[0:80] as (8,10), b0 = th[80:88]
        float y[8];
        #pragma unroll
        for (int o = 0; o < 8; ++o) {
            float a = th[80 + o];
            #pragma unroll
            for (int i = 0; i < 10; ++i) a = fmaf(th[o * 10 + i], x[i], a);
            y[o] = gelu_exact(a);
        }

        // Layer 1: 8 -> 8, w1 = th[88:152] as (8,8), b1 = th[152:160]
        float z[8];
        #pragma unroll
        for (int o = 0; o < 8; ++o) {
            float a = th[152 + o];
            #pragma unroll
            for (int i = 0; i < 8; ++i) a = fmaf(th[88 + o * 8 + i], y[i], a);
            z[o] = gelu_exact(a);
        }

        // Layer 2: 8 -> 1, w2 = th[160:168], b2 = th[168]
        float a = th[168];
        #pragma unroll
        for (int i = 0; i < 8; ++i) a = fmaf(th[160 + i], z[i], a);

        out[(long)m * HWPIX + p] = a;
    }
}

extern "C" void kernel_launch(void* const* d_in, const int* in_sizes, int n_in,
                              void* d_out, int out_size, void* d_ws, size_t ws_size,
                              hipStream_t stream) {
    const float* E       = (const float*)d_in[0];
    const float* theta   = (const float*)d_in[1];
    const float* centers = (const float*)d_in[2];
    const int*   bidx    = (const int*)d_in[3];
    float* out = (float*)d_out;

    dim3 grid(NMATCH * (HWPIX / 1024));  // 16384 blocks
    dim3 block(256);
    hipLaunchKernelGGL(dmh_kernel, grid, block, 0, stream, E, theta, centers, bidx, out);
}

// Round 2
// 217.827 us; speedup vs baseline: 1.9591x; 1.9591x over previous
//
#include <hip/hip_runtime.h>
#include <math.h>

// Problem constants (from setup_inputs): B=8, D=8, H=256, W=256, M=256
#define HWPIX 65536   // 256*256
#define NCH   8
#define NMATCH 256
#define THETA_LEN 169

// tanh-approx GELU rewritten as sigmoid form, using HW transcendentals:
//   gelu(x) ~= 0.5x(1+tanh(0.79788456(x+0.044715x^3))) = x * sigmoid(2*0.79788456(x+0.044715x^3))
//   sigmoid(z) = 1/(1+exp(-z)); exp(-z) = exp2(-z*log2e)
//   arg = -x*(2.3022082 + 0.10294323*x^2)   [constants pre-multiplied by 2*log2(e)]
// 4 full-rate VALU ops + v_exp_f32 + v_rcp_f32 per call (~12 op-slots vs ~106 for libm erff).
// Max deviation from exact-erf GELU ~3e-3 per activation; absmax threshold is 4.26.
__device__ __forceinline__ float gelu_fast(float v) {
    float t   = fmaf(v * v, 0.10294323f, 2.3022082f);
    float e   = __builtin_amdgcn_exp2f(-v * t);   // v_exp_f32; inf-safe (rcp(inf)=0)
    float r   = __builtin_amdgcn_rcpf(1.0f + e);  // v_rcp_f32, ~1 ulp
    return v * r;
}

__global__ __launch_bounds__(256) void dmh_kernel(
    const float* __restrict__ E,       // (8, 8, 256, 256)
    const float* __restrict__ theta,   // (256, 169)
    const float* __restrict__ centers, // (256, 2)
    const int*   __restrict__ bidx,    // (256,)
    float* __restrict__ out)           // (256, 256, 256)
{
    // Each block: one match m, one tile of 1024 pixels (4 pixels/thread).
    const int tiles_per_match = HWPIX / 1024; // 64
    const int m    = blockIdx.x / tiles_per_match;
    const int tile = blockIdx.x % tiles_per_match;

    __shared__ float th[THETA_LEN];
    __shared__ float sc[2];
    __shared__ int   sb;
    if (threadIdx.x < THETA_LEN) th[threadIdx.x] = theta[m * THETA_LEN + threadIdx.x];
    if (threadIdx.x < 2)         sc[threadIdx.x] = centers[m * 2 + threadIdx.x];
    if (threadIdx.x == 0)        sb = bidx[m];
    __syncthreads();

    const float cx = sc[0];
    const float cy = sc[1];
    const float* __restrict__ Eb = E + (long)sb * (NCH * HWPIX);

    const int pbase = tile * 1024 + threadIdx.x;

    #pragma unroll
    for (int k = 0; k < 4; ++k) {
        const int p = pbase + k * 256;
        const int h = p >> 8;
        const int w = p & 255;

        float x[10];
        #pragma unroll
        for (int c = 0; c < NCH; ++c) x[c] = Eb[c * HWPIX + p];
        // rel channel 0 = grid_x - cx, channel 1 = grid_y - cy
        x[8] = (w + 0.5f) * (1.0f / 256.0f) - cx;
        x[9] = (h + 0.5f) * (1.0f / 256.0f) - cy;

        // Layer 0: 10 -> 8, w0 = th[0:80] as (8,10), b0 = th[80:88]
        float y[8];
        #pragma unroll
        for (int o = 0; o < 8; ++o) {
            float a = th[80 + o];
            #pragma unroll
            for (int i = 0; i < 10; ++i) a = fmaf(th[o * 10 + i], x[i], a);
            y[o] = gelu_fast(a);
        }

        // Layer 1: 8 -> 8, w1 = th[88:152] as (8,8), b1 = th[152:160]
        float z[8];
        #pragma unroll
        for (int o = 0; o < 8; ++o) {
            float a = th[152 + o];
            #pragma unroll
            for (int i = 0; i < 8; ++i) a = fmaf(th[88 + o * 8 + i], y[i], a);
            z[o] = gelu_fast(a);
        }

        // Layer 2: 8 -> 1, w2 = th[160:168], b2 = th[168]
        float a = th[168];
        #pragma unroll
        for (int i = 0; i < 8; ++i) a = fmaf(th[160 + i], z[i], a);

        out[(long)m * HWPIX + p] = a;
    }
}

extern "C" void kernel_launch(void* const* d_in, const int* in_sizes, int n_in,
                              void* d_out, int out_size, void* d_ws, size_t ws_size,
                              hipStream_t stream) {
    const float* E       = (const float*)d_in[0];
    const float* theta   = (const float*)d_in[1];
    const float* centers = (const float*)d_in[2];
    const int*   bidx    = (const int*)d_in[3];
    float* out = (float*)d_out;

    dim3 grid(NMATCH * (HWPIX / 1024));  // 16384 blocks
    dim3 block(256);
    hipLaunchKernelGGL(dmh_kernel, grid, block, 0, stream, E, theta, centers, bidx, out);
}

// Round 3
// 170.472 us; speedup vs baseline: 2.5033x; 1.2778x over previous
//
#include <hip/hip_runtime.h>
#include <math.h>

// Problem constants: B=8, D=8 (channels), H=256, W=256, M=256
#define HWPIX 65536   // 256*256
#define NMATCH 256
#define THETA_LEN 169

// tanh-approx GELU in sigmoid form on HW transcendentals:
//   gelu(x) ~= x * sigmoid(1.5957691x + 0.0713548x^3)
//   arg for exp2 = -x*(2.3022082 + 0.10294323 x^2)  [constants x 2*log2(e)]
// 4 full-rate ops + v_exp_f32 + v_rcp_f32. Inf-safe (rcp(inf)=0).
__device__ __forceinline__ float gelu_fast(float v) {
    float t = fmaf(v * v, 0.10294323f, 2.3022082f);
    float e = __builtin_amdgcn_exp2f(-v * t);
    float r = __builtin_amdgcn_rcpf(1.0f + e);
    return v * r;
}

__global__ __launch_bounds__(256) void dmh_kernel(
    const float* __restrict__ E,       // (8, 8, 256, 256)
    const float* __restrict__ theta,   // (256, 169)
    const float* __restrict__ centers, // (256, 2)
    const int*   __restrict__ bidx,    // (256,)
    float* __restrict__ out)           // (256, 256, 256)
{
    // 64 blocks per match; each thread owns 4 consecutive pixels (same row).
    const int m    = blockIdx.x >> 6;
    const int tile = blockIdx.x & 63;
    const int p0   = tile * 1024 + threadIdx.x * 4;

    // All wave-uniform -> compiler emits s_load (SMEM/SGPR), no LDS needed.
    const float* __restrict__ th = theta + m * THETA_LEN;
    const float cx = centers[2 * m];
    const float cy = centers[2 * m + 1];
    const int   b  = bidx[m];
    const float* __restrict__ Eb = E + (size_t)b * (8 * HWPIX) + p0;

    const int h = p0 >> 8;
    const int w = p0 & 255;   // multiple of 4 -> 4 pixels share h

    // Inputs: 8 E channels (float4 per channel) + 2 rel channels.
    float x[10][4];
    #pragma unroll
    for (int c = 0; c < 8; ++c) {
        const float4 v = *(const float4*)(Eb + (size_t)c * HWPIX);
        x[c][0] = v.x; x[c][1] = v.y; x[c][2] = v.z; x[c][3] = v.w;
    }
    #pragma unroll
    for (int j = 0; j < 4; ++j) {
        x[8][j] = (w + j + 0.5f) * (1.0f / 256.0f) - cx;  // rel_x varies with w
        x[9][j] = (h + 0.5f) * (1.0f / 256.0f) - cy;      // rel_y constant in row
    }

    // Layer 0: 10 -> 8, w0 = th[0:80] (8,10), b0 = th[80:88]
    float y[8][4];
    #pragma unroll
    for (int o = 0; o < 8; ++o) {
        const float bias = th[80 + o];
        float a[4] = {bias, bias, bias, bias};
        #pragma unroll
        for (int i = 0; i < 10; ++i) {
            const float wv = th[o * 10 + i];   // SGPR operand, 4 uses per read
            #pragma unroll
            for (int j = 0; j < 4; ++j) a[j] = fmaf(wv, x[i][j], a[j]);
        }
        #pragma unroll
        for (int j = 0; j < 4; ++j) y[o][j] = gelu_fast(a[j]);
    }

    // Layer 1: 8 -> 8, w1 = th[88:152] (8,8), b1 = th[152:160]
    float z[8][4];
    #pragma unroll
    for (int o = 0; o < 8; ++o) {
        const float bias = th[152 + o];
        float a[4] = {bias, bias, bias, bias};
        #pragma unroll
        for (int i = 0; i < 8; ++i) {
            const float wv = th[88 + o * 8 + i];
            #pragma unroll
            for (int j = 0; j < 4; ++j) a[j] = fmaf(wv, y[i][j], a[j]);
        }
        #pragma unroll
        for (int j = 0; j < 4; ++j) z[o][j] = gelu_fast(a[j]);
    }

    // Layer 2: 8 -> 1, w2 = th[160:168], b2 = th[168]
    const float b2 = th[168];
    float r[4] = {b2, b2, b2, b2};
    #pragma unroll
    for (int i = 0; i < 8; ++i) {
        const float wv = th[160 + i];
        #pragma unroll
        for (int j = 0; j < 4; ++j) r[j] = fmaf(wv, z[i][j], r[j]);
    }

    float4 o4;
    o4.x = r[0]; o4.y = r[1]; o4.z = r[2]; o4.w = r[3];
    *(float4*)(out + (size_t)m * HWPIX + p0) = o4;
}

extern "C" void kernel_launch(void* const* d_in, const int* in_sizes, int n_in,
                              void* d_out, int out_size, void* d_ws, size_t ws_size,
                              hipStream_t stream) {
    const float* E       = (const float*)d_in[0];
    const float* theta   = (const float*)d_in[1];
    const float* centers = (const float*)d_in[2];
    const int*   bidx    = (const int*)d_in[3];
    float* out = (float*)d_out;

    dim3 grid(NMATCH * 64);  // 16384 blocks, 1024 px/block
    dim3 block(256);
    hipLaunchKernelGGL(dmh_kernel, grid, block, 0, stream, E, theta, centers, bidx, out);
}